// Round 11
// baseline (834.241 us; speedup 1.0000x reference)
//
#include <hip/hip_runtime.h>
#include <hip/hip_fp16.h>
#include <math.h>

// GCN encoder, N=100000, E=1600000, C_IN=32, C_H=C_OUT=64, G=64.
// CSR build via two-level LDS counting sort (NO global atomics).
// em weight = ew*dis[dst]; dis[src] folded into features. FP16 features.
// Fused agg+matmul+bias+SiLU per layer; pair-gather (2 edges/instr via wave
// halves; layer1 4 edges/instr via quarters); edge meta staged in LDS.
// R11: revert R10's batched epilogue (regressed: W reloads were NOT the
// bottleneck). Gather-latency bound at 33% occupancy -> force 8 waves/EU
// (__launch_bounds__(256,8); VGPR already ~60) + 2x grid for balance.

#define NB   256        // dst buckets (512 nodes each; supports N < 131072)
#define PBLK 1024       // partition blocks
#define FIXP_SCALE 1048576.0f   // 2^20
#define FIXP_MASK  ((1ULL << 40) - 1)

__device__ __forceinline__ int lower_bound_i(const int* __restrict__ a, int n, int v) {
    int lo = 0, hi = n;
    while (lo < hi) {
        int m = (lo + hi) >> 1;
        if (a[m] < v) lo = m + 1; else hi = m;
    }
    return lo;
}

// A1: per-block histogram over 256 dst-buckets (LDS atomics only)
__global__ __launch_bounds__(256) void k_bhist(const int* __restrict__ dst,
                                               int* __restrict__ hcnt, int e) {
    __shared__ int hist[NB];
    int tid = threadIdx.x, blk = blockIdx.x;
    hist[tid] = 0;
    __syncthreads();
    int chunk = (e + PBLK - 1) / PBLK;
    int lo = blk * chunk, hi = min(e, lo + chunk);
    for (int i = lo + tid; i < hi; i += 256)
        atomicAdd(&hist[dst[i] >> 9], 1);
    __syncthreads();
    hcnt[tid * PBLK + blk] = hist[tid];   // [bucket][block] layout
}

// A2a: per-bucket exclusive scan across the PBLK block-counts (in place) + totals
__global__ __launch_bounds__(256) void k_bscan(int* __restrict__ hcnt,
                                               int* __restrict__ btot) {
    __shared__ int s[256];
    int b = blockIdx.x, tid = threadIdx.x;
    int* row = hcnt + b * PBLK;
    int a0 = row[4 * tid], a1 = row[4 * tid + 1], a2 = row[4 * tid + 2], a3 = row[4 * tid + 3];
    int tsum = a0 + a1 + a2 + a3;
    s[tid] = tsum;
    __syncthreads();
    for (int off = 1; off < 256; off <<= 1) {
        int t = (tid >= off) ? s[tid - off] : 0;
        __syncthreads();
        s[tid] += t;
        __syncthreads();
    }
    int ex = s[tid] - tsum;
    row[4 * tid] = ex;
    row[4 * tid + 1] = ex + a0;
    row[4 * tid + 2] = ex + a0 + a1;
    row[4 * tid + 3] = ex + a0 + a1 + a2;
    if (tid == 255) btot[b] = s[255];
}

// A2b: scan bucket totals -> bucket_base[NB+1]; also rowptr[n]=e
__global__ __launch_bounds__(256) void k_bbase(const int* __restrict__ btot,
                                               int* __restrict__ bbase,
                                               int* __restrict__ rowptr, int n, int e) {
    __shared__ int s[256];
    int tid = threadIdx.x;
    int v = btot[tid];
    s[tid] = v;
    __syncthreads();
    for (int off = 1; off < 256; off <<= 1) {
        int t = (tid >= off) ? s[tid - off] : 0;
        __syncthreads();
        s[tid] += t;
        __syncthreads();
    }
    bbase[tid] = s[tid] - v;
    if (tid == 255) bbase[NB] = s[255];   // == e
    if (tid == 0) rowptr[n] = e;
}

// A3: partition edges into buckets; pos from LDS cursor (no global atomics)
__global__ __launch_bounds__(256) void k_bpart(const int* __restrict__ src,
                                               const int* __restrict__ dst,
                                               const float* __restrict__ ew,
                                               const int* __restrict__ hcnt,
                                               const int* __restrict__ bbase,
                                               int2* __restrict__ bedge, int e) {
    __shared__ int cur[NB];
    int tid = threadIdx.x, blk = blockIdx.x;
    cur[tid] = bbase[tid] + hcnt[tid * PBLK + blk];
    __syncthreads();
    int chunk = (e + PBLK - 1) / PBLK;
    int lo = blk * chunk, hi = min(e, lo + chunk);
    for (int i = lo + tid; i < hi; i += 256) {
        int d = dst[i];
        int pos = atomicAdd(&cur[d >> 9], 1);            // LDS atomic
        bedge[pos] = make_int2(src[i] | ((d & 511) << 17), __float_as_int(ew[i]));
    }
}

// B: per-bucket (512 nodes): LDS packed cnt + fixp sum(ew) -> dis, rowptr,
// then scatter (src, ew*dis[d]) grouped per node into em. No global atomics.
__global__ __launch_bounds__(256) void k_bucket(const int2* __restrict__ bedge,
                                                const int* __restrict__ bbase,
                                                float* __restrict__ dis,
                                                int* __restrict__ rowptr,
                                                int2* __restrict__ em, int n) {
    __shared__ unsigned long long pk[512];
    __shared__ int cnt[512];
    __shared__ int scn[512];
    __shared__ float sdis[512];
    __shared__ int cur[512];
    int b = blockIdx.x, tid = threadIdx.x;
    int e0 = bbase[b], e1 = bbase[b + 1];
    pk[tid] = 0ULL; pk[tid + 256] = 0ULL;
    __syncthreads();
    for (int i = e0 + tid; i < e1; i += 256) {
        int2 v = bedge[i];
        int dlo = (v.x >> 17) & 511;
        unsigned long long p =
            (1ULL << 40) | (unsigned long long)(__int_as_float(v.y) * FIXP_SCALE);
        atomicAdd(&pk[dlo], p);                          // LDS atomic
    }
    __syncthreads();
#pragma unroll
    for (int k = 0; k < 2; ++k) {
        int i = tid + k * 256;
        unsigned long long v = pk[i];
        int c = (int)(v >> 40);
        cnt[i] = c; scn[i] = c;
        sdis[i] = rsqrtf(1.0f + (float)(v & FIXP_MASK) * (1.0f / FIXP_SCALE));
    }
    __syncthreads();
    // 512-entry inclusive scan, 2 elems/thread, read-all-then-write-all
    for (int off = 1; off < 512; off <<= 1) {
        int i0 = tid, i1 = tid + 256;
        int v0 = (i0 >= off) ? scn[i0 - off] : 0;
        int v1 = (i1 >= off) ? scn[i1 - off] : 0;
        __syncthreads();
        scn[i0] += v0; scn[i1] += v1;
        __syncthreads();
    }
#pragma unroll
    for (int k = 0; k < 2; ++k) {
        int i = tid + k * 256;
        int rb = e0 + scn[i] - cnt[i];                   // exclusive
        cur[i] = rb;
        int node = (b << 9) + i;
        if (node < n) { rowptr[node] = rb; dis[node] = sdis[i]; }
    }
    __syncthreads();
    for (int i = e0 + tid; i < e1; i += 256) {
        int2 v = bedge[i];
        int dlo = (v.x >> 17) & 511;
        int pos = atomicAdd(&cur[dlo], 1);               // LDS atomic
        float w = __int_as_float(v.y) * sdis[dlo];
        em[pos] = make_int2(v.x & 0x1FFFF, __float_as_int(w));
    }
}

// hs = fp16(dis * x)  (layer-1 feature pre-scale, 32 channels)
__global__ void k_scale(const float* __restrict__ x, const float* __restrict__ dis,
                        __half* __restrict__ hs, int total) {
    int idx = blockIdx.x * blockDim.x + threadIdx.x;
    if (idx < total) hs[idx] = __float2half(x[idx] * dis[idx >> 5]);
}

__device__ __forceinline__ float2 cvt_pair(unsigned int u) {
    __half2 h2 = *(__half2*)&u;
    return __half22float2(h2);
}

// Fused agg + 64x64 matvec + bias + SiLU (+dis prescale). FP16 features.
// Pair-gather: lane = channel-pair c (uint load = 2 fp16), wave halves take
// even/odd edges -> one gather instruction covers 2 edges. Edge meta staged
// in LDS, per-half uniform ds_read_b64 (broadcast).
template <bool SCALE, typename OUT>
__global__ __launch_bounds__(256, 8) void k_aggmm64(const __half* __restrict__ h,
                                                    const int2* __restrict__ em,
                                                    const int* __restrict__ rowptr,
                                                    const float* __restrict__ dis,
                                                    const float* __restrict__ W,
                                                    const float* __restrict__ bias,
                                                    OUT* __restrict__ out, int n) {
    __shared__ __align__(16) float sacc[4][64];
    __shared__ __align__(8) int2 sme[4][64];
    int lane = threadIdx.x & 63, wv = threadIdx.x >> 6;
    int c = lane & 31, half = lane >> 5;
    const unsigned int* h32 = (const unsigned int*)h;
    float bv = bias[lane];
    int wid = (blockIdx.x * blockDim.x + threadIdx.x) >> 6;
    int nw = (gridDim.x * blockDim.x) >> 6;
    for (int node = wid; node < n; node += nw) {
        int lo = rowptr[node], hi = rowptr[node + 1];
        int deg = hi - lo;
        float2 acc = make_float2(0.0f, 0.0f);
        if (half == 0) {
            float2 hv = cvt_pair(h32[(size_t)node * 32 + c]);
            float di = dis[node];
            acc.x = di * hv.x; acc.y = di * hv.y;        // di^2*h = di*hs
        }
        for (int jb = 0; jb < deg; jb += 64) {
            int idx = lo + jb + lane;
            int2 me = (idx < hi) ? em[idx] : make_int2(0, 0);  // w=0 pad
            sme[wv][lane] = me;
            int rem = deg - jb;
#pragma unroll
            for (int g = 0; g < 4; ++g) {
                if (g * 16 < rem) {
#pragma unroll
                    for (int t = 0; t < 8; ++t) {
                        int2 ev = sme[wv][g * 16 + 2 * t + half];  // per-half bcast
                        float ww = __int_as_float(ev.y);
                        float2 hf = cvt_pair(h32[(size_t)ev.x * 32 + c]);
                        acc.x = fmaf(ww, hf.x, acc.x);
                        acc.y = fmaf(ww, hf.y, acc.y);
                    }
                }
            }
        }
        // cross-half reduce, then channel-pair layout into sacc
        acc.x += __shfl_down(acc.x, 32, 64);
        acc.y += __shfl_down(acc.y, 32, 64);
        if (half == 0) ((float2*)sacc[wv])[c] = acc;     // floats 2c, 2c+1
        float o = bv;
        const float4* s4 = (const float4*)sacc[wv];
#pragma unroll
        for (int k4 = 0; k4 < 16; ++k4) {
            float4 a4 = s4[k4];                 // same addr all lanes: broadcast
            o = fmaf(a4.x, W[(4 * k4 + 0) * 64 + lane], o);
            o = fmaf(a4.y, W[(4 * k4 + 1) * 64 + lane], o);
            o = fmaf(a4.z, W[(4 * k4 + 2) * 64 + lane], o);
            o = fmaf(a4.w, W[(4 * k4 + 3) * 64 + lane], o);
        }
        o = o / (1.0f + __expf(-o));
        if (SCALE) o *= dis[node];
        if (sizeof(OUT) == 2) {
            ((__half*)out)[(size_t)node * 64 + lane] = __float2half(o);
        } else {
            ((float*)out)[(size_t)node * 64 + lane] = o;
        }
    }
}

// Fused layer-1 (32-ch fp16 input): lane = channel-pair c (16 dwords/row),
// wave quarters take edges mod 4 -> 4 edges per gather instruction.
__global__ __launch_bounds__(256, 8) void k_aggmm32(const __half* __restrict__ h,
                                                    const int2* __restrict__ em,
                                                    const int* __restrict__ rowptr,
                                                    const float* __restrict__ dis,
                                                    const float* __restrict__ W,
                                                    const float* __restrict__ bias,
                                                    __half* __restrict__ out, int n) {
    __shared__ __align__(16) float sacc[4][32];
    __shared__ __align__(8) int2 sme[4][64];
    int lane = threadIdx.x & 63, wv = threadIdx.x >> 6;
    int c = lane & 15, quarter = lane >> 4;
    const unsigned int* h32 = (const unsigned int*)h;
    float bv = bias[lane];
    int wid = (blockIdx.x * blockDim.x + threadIdx.x) >> 6;
    int nw = (gridDim.x * blockDim.x) >> 6;
    for (int node = wid; node < n; node += nw) {
        int lo = rowptr[node], hi = rowptr[node + 1];
        int deg = hi - lo;
        float2 acc = make_float2(0.0f, 0.0f);
        if (quarter == 0) {
            float2 hv = cvt_pair(h32[(size_t)node * 16 + c]);
            float di = dis[node];
            acc.x = di * hv.x; acc.y = di * hv.y;
        }
        for (int jb = 0; jb < deg; jb += 64) {
            int idx = lo + jb + lane;
            int2 me = (idx < hi) ? em[idx] : make_int2(0, 0);  // w=0 pad
            sme[wv][lane] = me;
            int rem = deg - jb;
#pragma unroll
            for (int g = 0; g < 4; ++g) {
                if (g * 16 < rem) {
#pragma unroll
                    for (int t = 0; t < 4; ++t) {
                        int2 ev = sme[wv][g * 16 + 4 * t + quarter];  // per-quarter bcast
                        float ww = __int_as_float(ev.y);
                        float2 hf = cvt_pair(h32[(size_t)ev.x * 16 + c]);
                        acc.x = fmaf(ww, hf.x, acc.x);
                        acc.y = fmaf(ww, hf.y, acc.y);
                    }
                }
            }
        }
        // cross-quarter reduce (q0+=q2, q1+=q3; then q0+=q1)
        acc.x += __shfl_down(acc.x, 32, 64);
        acc.y += __shfl_down(acc.y, 32, 64);
        acc.x += __shfl_down(acc.x, 16, 64);
        acc.y += __shfl_down(acc.y, 16, 64);
        if (quarter == 0) ((float2*)sacc[wv])[c] = acc;  // floats 2c, 2c+1
        float o = bv;
        const float4* s4 = (const float4*)sacc[wv];
#pragma unroll
        for (int k4 = 0; k4 < 8; ++k4) {
            float4 a4 = s4[k4];
            o = fmaf(a4.x, W[(4 * k4 + 0) * 64 + lane], o);
            o = fmaf(a4.y, W[(4 * k4 + 1) * 64 + lane], o);
            o = fmaf(a4.z, W[(4 * k4 + 2) * 64 + lane], o);
            o = fmaf(a4.w, W[(4 * k4 + 3) * 64 + lane], o);
        }
        o = o / (1.0f + __expf(-o));
        o *= dis[node];
        out[(size_t)node * 64 + lane] = __float2half(o);
    }
}

// pool phase 1: 128-row chunks, segment-flush atomics into acc[G*64]
__global__ void k_pool_partial(const float* __restrict__ h, const int* __restrict__ batch,
                               float* __restrict__ acc, int n) {
    int c = threadIdx.x & 63, r = threadIdx.x >> 6;
    int base = blockIdx.x * 128;
    int end = base + 128; if (end > n) end = n;
    float part = 0.0f;
    int cur = -1;
    for (int i = base + r; i < end; i += 4) {
        int g = batch[i];
        if (g != cur) {
            if (cur >= 0) atomicAdd(&acc[cur * 64 + c], part);
            part = 0.0f;
            cur = g;
        }
        part += h[(size_t)i * 64 + c];
    }
    if (cur >= 0) atomicAdd(&acc[cur * 64 + c], part);
}

// pool phase 2: divide by per-graph count
__global__ void k_pool_final(const float* __restrict__ acc, const int* __restrict__ batch,
                             float* __restrict__ out, int n) {
    int idx = blockIdx.x * blockDim.x + threadIdx.x;   // G*64 threads
    int g = idx >> 6;
    int lo = lower_bound_i(batch, n, g);
    int hi = lower_bound_i(batch, n, g + 1);
    int cnt = hi - lo;
    out[idx] = acc[idx] / (float)(cnt > 0 ? cnt : 1);
}

extern "C" void kernel_launch(void* const* d_in, const int* in_sizes, int n_in,
                              void* d_out, int out_size, void* d_ws, size_t ws_size,
                              hipStream_t stream) {
    const float* x   = (const float*)d_in[0];
    const float* ew  = (const float*)d_in[1];
    const float* W1  = (const float*)d_in[2];
    const float* b1  = (const float*)d_in[3];
    const float* W2  = (const float*)d_in[4];
    const float* b2  = (const float*)d_in[5];
    const float* W3  = (const float*)d_in[6];
    const float* b3  = (const float*)d_in[7];
    const int*   eidx  = (const int*)d_in[8];
    const int*   batch = (const int*)d_in[9];
    float* out = (float*)d_out;

    const int E = in_sizes[1];       // 1,600,000
    const int N = in_sizes[9];       // 100,000 (< 131072: fits 17-bit src pack)
    const int G = 64;
    const int* src = eidx;
    const int* dst = eidx + E;

    // workspace: A/B (fp16 features) double as CSR-build scratch
    // (bedge in A: E*8B == N*64*2B exactly; hcnt/btot in B), both dead by the
    // time features first touch them. C holds the final fp32 layer for pooling.
    char* p = (char*)d_ws;
    __half* A     = (__half*)p;                p += (size_t)N * 64 * sizeof(__half);
    __half* B     = (__half*)p;                p += (size_t)N * 64 * sizeof(__half);
    float* C      = (float*)p;                 p += (size_t)N * 64 * sizeof(float);
    float* dis    = (float*)p;                 p += (size_t)N * sizeof(float);
    int*   rowptr = (int*)p;                   p += (size_t)(N + 1) * sizeof(int);
    int*   bbase  = (int*)p;                   p += (size_t)(NB + 1) * sizeof(int);
    float* acc    = (float*)p;                 p += (size_t)G * 64 * sizeof(float);
    p = (char*)(((uintptr_t)p + 7) & ~(uintptr_t)7);
    int2*  em     = (int2*)p;                  // E entries, 8B

    int2* bedge = (int2*)A;                    // E*8B == N*64*2B
    int*  hcnt  = (int*)B;                     // NB*PBLK*4B = 1MB
    int*  btot  = (int*)B + NB * PBLK;         // NB ints

    const int BT = 256;
    const int FUSED_BLOCKS = 6250;             // 25000 waves x 4 nodes = 100k

    // --- CSR build: LDS counting sort, zero global atomics ---
    k_bhist<<<PBLK, 256, 0, stream>>>(dst, hcnt, E);
    k_bscan<<<NB, 256, 0, stream>>>(hcnt, btot);
    k_bbase<<<1, 256, 0, stream>>>(btot, bbase, rowptr, N, E);
    k_bpart<<<PBLK, 256, 0, stream>>>(src, dst, ew, hcnt, bbase, bedge, E);
    k_bucket<<<NB, 256, 0, stream>>>(bedge, bbase, dis, rowptr, em, N);

    // --- layer 1: hs1 = fp16(dis*x) -> B ; fused agg+mm+silu*dis -> A ---
    // (B's hcnt scratch is dead after k_bpart; A's bedge dead after k_bucket)
    k_scale<<<(N * 32 + BT - 1) / BT, BT, 0, stream>>>(x, dis, (__half*)B, N * 32);
    k_aggmm32<<<FUSED_BLOCKS, BT, 0, stream>>>((__half*)B, em, rowptr, dis, W1, b1, A, N);

    // --- layer 2: fused agg+mm+silu*dis -> B ---
    k_aggmm64<true, __half><<<FUSED_BLOCKS, BT, 0, stream>>>(A, em, rowptr, dis, W2, b2, B, N);

    // --- layer 3: fused agg+mm+silu (raw fp32, for pooling) -> C ---
    k_aggmm64<false, float><<<FUSED_BLOCKS, BT, 0, stream>>>(B, em, rowptr, dis, W3, b3, C, N);

    // --- mean pool ---
    hipMemsetAsync(acc, 0, (size_t)G * 64 * sizeof(float), stream);
    k_pool_partial<<<(N + 127) / 128, BT, 0, stream>>>(C, batch, acc, N);
    k_pool_final<<<(G * 64) / BT, BT, 0, stream>>>(acc, batch, out, N);
}

// Round 12
// 779.571 us; speedup vs baseline: 1.0701x; 1.0701x over previous
//
#include <hip/hip_runtime.h>
#include <hip/hip_fp16.h>
#include <math.h>

// GCN encoder, N=100000, E=1600000, C_IN=32, C_H=C_OUT=64, G=64.
// CSR build via two-level LDS counting sort (NO global atomics).
// em weight = ew*dis[dst]; dis[src] folded into features. FP16 features.
// Fused agg+matmul+bias+SiLU per layer; pair-gather (2 edges/instr via wave
// halves; layer1 4 edges/instr via quarters); edge meta staged in LDS.
// R12: __launch_bounds__(256,6) — 24 waves/CU (was 16) WITHOUT starving the
// allocator (85-VGPR cap >= kernel's ~64). R11's (256,8) forced 32 VGPRs and
// spilled to scratch (FETCH 718 MB): never cap below ~64 here.

#define NB   256        // dst buckets (512 nodes each; supports N < 131072)
#define PBLK 1024       // partition blocks
#define FIXP_SCALE 1048576.0f   // 2^20
#define FIXP_MASK  ((1ULL << 40) - 1)

__device__ __forceinline__ int lower_bound_i(const int* __restrict__ a, int n, int v) {
    int lo = 0, hi = n;
    while (lo < hi) {
        int m = (lo + hi) >> 1;
        if (a[m] < v) lo = m + 1; else hi = m;
    }
    return lo;
}

// A1: per-block histogram over 256 dst-buckets (LDS atomics only)
__global__ __launch_bounds__(256) void k_bhist(const int* __restrict__ dst,
                                               int* __restrict__ hcnt, int e) {
    __shared__ int hist[NB];
    int tid = threadIdx.x, blk = blockIdx.x;
    hist[tid] = 0;
    __syncthreads();
    int chunk = (e + PBLK - 1) / PBLK;
    int lo = blk * chunk, hi = min(e, lo + chunk);
    for (int i = lo + tid; i < hi; i += 256)
        atomicAdd(&hist[dst[i] >> 9], 1);
    __syncthreads();
    hcnt[tid * PBLK + blk] = hist[tid];   // [bucket][block] layout
}

// A2a: per-bucket exclusive scan across the PBLK block-counts (in place) + totals
__global__ __launch_bounds__(256) void k_bscan(int* __restrict__ hcnt,
                                               int* __restrict__ btot) {
    __shared__ int s[256];
    int b = blockIdx.x, tid = threadIdx.x;
    int* row = hcnt + b * PBLK;
    int a0 = row[4 * tid], a1 = row[4 * tid + 1], a2 = row[4 * tid + 2], a3 = row[4 * tid + 3];
    int tsum = a0 + a1 + a2 + a3;
    s[tid] = tsum;
    __syncthreads();
    for (int off = 1; off < 256; off <<= 1) {
        int t = (tid >= off) ? s[tid - off] : 0;
        __syncthreads();
        s[tid] += t;
        __syncthreads();
    }
    int ex = s[tid] - tsum;
    row[4 * tid] = ex;
    row[4 * tid + 1] = ex + a0;
    row[4 * tid + 2] = ex + a0 + a1;
    row[4 * tid + 3] = ex + a0 + a1 + a2;
    if (tid == 255) btot[b] = s[255];
}

// A2b: scan bucket totals -> bucket_base[NB+1]; also rowptr[n]=e
__global__ __launch_bounds__(256) void k_bbase(const int* __restrict__ btot,
                                               int* __restrict__ bbase,
                                               int* __restrict__ rowptr, int n, int e) {
    __shared__ int s[256];
    int tid = threadIdx.x;
    int v = btot[tid];
    s[tid] = v;
    __syncthreads();
    for (int off = 1; off < 256; off <<= 1) {
        int t = (tid >= off) ? s[tid - off] : 0;
        __syncthreads();
        s[tid] += t;
        __syncthreads();
    }
    bbase[tid] = s[tid] - v;
    if (tid == 255) bbase[NB] = s[255];   // == e
    if (tid == 0) rowptr[n] = e;
}

// A3: partition edges into buckets; pos from LDS cursor (no global atomics)
__global__ __launch_bounds__(256) void k_bpart(const int* __restrict__ src,
                                               const int* __restrict__ dst,
                                               const float* __restrict__ ew,
                                               const int* __restrict__ hcnt,
                                               const int* __restrict__ bbase,
                                               int2* __restrict__ bedge, int e) {
    __shared__ int cur[NB];
    int tid = threadIdx.x, blk = blockIdx.x;
    cur[tid] = bbase[tid] + hcnt[tid * PBLK + blk];
    __syncthreads();
    int chunk = (e + PBLK - 1) / PBLK;
    int lo = blk * chunk, hi = min(e, lo + chunk);
    for (int i = lo + tid; i < hi; i += 256) {
        int d = dst[i];
        int pos = atomicAdd(&cur[d >> 9], 1);            // LDS atomic
        bedge[pos] = make_int2(src[i] | ((d & 511) << 17), __float_as_int(ew[i]));
    }
}

// B: per-bucket (512 nodes): LDS packed cnt + fixp sum(ew) -> dis, rowptr,
// then scatter (src, ew*dis[d]) grouped per node into em. No global atomics.
__global__ __launch_bounds__(256) void k_bucket(const int2* __restrict__ bedge,
                                                const int* __restrict__ bbase,
                                                float* __restrict__ dis,
                                                int* __restrict__ rowptr,
                                                int2* __restrict__ em, int n) {
    __shared__ unsigned long long pk[512];
    __shared__ int cnt[512];
    __shared__ int scn[512];
    __shared__ float sdis[512];
    __shared__ int cur[512];
    int b = blockIdx.x, tid = threadIdx.x;
    int e0 = bbase[b], e1 = bbase[b + 1];
    pk[tid] = 0ULL; pk[tid + 256] = 0ULL;
    __syncthreads();
    for (int i = e0 + tid; i < e1; i += 256) {
        int2 v = bedge[i];
        int dlo = (v.x >> 17) & 511;
        unsigned long long p =
            (1ULL << 40) | (unsigned long long)(__int_as_float(v.y) * FIXP_SCALE);
        atomicAdd(&pk[dlo], p);                          // LDS atomic
    }
    __syncthreads();
#pragma unroll
    for (int k = 0; k < 2; ++k) {
        int i = tid + k * 256;
        unsigned long long v = pk[i];
        int c = (int)(v >> 40);
        cnt[i] = c; scn[i] = c;
        sdis[i] = rsqrtf(1.0f + (float)(v & FIXP_MASK) * (1.0f / FIXP_SCALE));
    }
    __syncthreads();
    // 512-entry inclusive scan, 2 elems/thread, read-all-then-write-all
    for (int off = 1; off < 512; off <<= 1) {
        int i0 = tid, i1 = tid + 256;
        int v0 = (i0 >= off) ? scn[i0 - off] : 0;
        int v1 = (i1 >= off) ? scn[i1 - off] : 0;
        __syncthreads();
        scn[i0] += v0; scn[i1] += v1;
        __syncthreads();
    }
#pragma unroll
    for (int k = 0; k < 2; ++k) {
        int i = tid + k * 256;
        int rb = e0 + scn[i] - cnt[i];                   // exclusive
        cur[i] = rb;
        int node = (b << 9) + i;
        if (node < n) { rowptr[node] = rb; dis[node] = sdis[i]; }
    }
    __syncthreads();
    for (int i = e0 + tid; i < e1; i += 256) {
        int2 v = bedge[i];
        int dlo = (v.x >> 17) & 511;
        int pos = atomicAdd(&cur[dlo], 1);               // LDS atomic
        float w = __int_as_float(v.y) * sdis[dlo];
        em[pos] = make_int2(v.x & 0x1FFFF, __float_as_int(w));
    }
}

// hs = fp16(dis * x)  (layer-1 feature pre-scale, 32 channels)
__global__ void k_scale(const float* __restrict__ x, const float* __restrict__ dis,
                        __half* __restrict__ hs, int total) {
    int idx = blockIdx.x * blockDim.x + threadIdx.x;
    if (idx < total) hs[idx] = __float2half(x[idx] * dis[idx >> 5]);
}

__device__ __forceinline__ float2 cvt_pair(unsigned int u) {
    __half2 h2 = *(__half2*)&u;
    return __half22float2(h2);
}

// Fused agg + 64x64 matvec + bias + SiLU (+dis prescale). FP16 features.
// Pair-gather: lane = channel-pair c (uint load = 2 fp16), wave halves take
// even/odd edges -> one gather instruction covers 2 edges. Edge meta staged
// in LDS, per-half uniform ds_read_b64 (broadcast).
template <bool SCALE, typename OUT>
__global__ __launch_bounds__(256, 6) void k_aggmm64(const __half* __restrict__ h,
                                                    const int2* __restrict__ em,
                                                    const int* __restrict__ rowptr,
                                                    const float* __restrict__ dis,
                                                    const float* __restrict__ W,
                                                    const float* __restrict__ bias,
                                                    OUT* __restrict__ out, int n) {
    __shared__ __align__(16) float sacc[4][64];
    __shared__ __align__(8) int2 sme[4][64];
    int lane = threadIdx.x & 63, wv = threadIdx.x >> 6;
    int c = lane & 31, half = lane >> 5;
    const unsigned int* h32 = (const unsigned int*)h;
    float bv = bias[lane];
    int wid = (blockIdx.x * blockDim.x + threadIdx.x) >> 6;
    int nw = (gridDim.x * blockDim.x) >> 6;
    for (int node = wid; node < n; node += nw) {
        int lo = rowptr[node], hi = rowptr[node + 1];
        int deg = hi - lo;
        float2 acc = make_float2(0.0f, 0.0f);
        if (half == 0) {
            float2 hv = cvt_pair(h32[(size_t)node * 32 + c]);
            float di = dis[node];
            acc.x = di * hv.x; acc.y = di * hv.y;        // di^2*h = di*hs
        }
        for (int jb = 0; jb < deg; jb += 64) {
            int idx = lo + jb + lane;
            int2 me = (idx < hi) ? em[idx] : make_int2(0, 0);  // w=0 pad
            sme[wv][lane] = me;
            int rem = deg - jb;
#pragma unroll
            for (int g = 0; g < 4; ++g) {
                if (g * 16 < rem) {
#pragma unroll
                    for (int t = 0; t < 8; ++t) {
                        int2 ev = sme[wv][g * 16 + 2 * t + half];  // per-half bcast
                        float ww = __int_as_float(ev.y);
                        float2 hf = cvt_pair(h32[(size_t)ev.x * 32 + c]);
                        acc.x = fmaf(ww, hf.x, acc.x);
                        acc.y = fmaf(ww, hf.y, acc.y);
                    }
                }
            }
        }
        // cross-half reduce, then channel-pair layout into sacc
        acc.x += __shfl_down(acc.x, 32, 64);
        acc.y += __shfl_down(acc.y, 32, 64);
        if (half == 0) ((float2*)sacc[wv])[c] = acc;     // floats 2c, 2c+1
        float o = bv;
        const float4* s4 = (const float4*)sacc[wv];
#pragma unroll
        for (int k4 = 0; k4 < 16; ++k4) {
            float4 a4 = s4[k4];                 // same addr all lanes: broadcast
            o = fmaf(a4.x, W[(4 * k4 + 0) * 64 + lane], o);
            o = fmaf(a4.y, W[(4 * k4 + 1) * 64 + lane], o);
            o = fmaf(a4.z, W[(4 * k4 + 2) * 64 + lane], o);
            o = fmaf(a4.w, W[(4 * k4 + 3) * 64 + lane], o);
        }
        o = o / (1.0f + __expf(-o));
        if (SCALE) o *= dis[node];
        if (sizeof(OUT) == 2) {
            ((__half*)out)[(size_t)node * 64 + lane] = __float2half(o);
        } else {
            ((float*)out)[(size_t)node * 64 + lane] = o;
        }
    }
}

// Fused layer-1 (32-ch fp16 input): lane = channel-pair c (16 dwords/row),
// wave quarters take edges mod 4 -> 4 edges per gather instruction.
__global__ __launch_bounds__(256, 6) void k_aggmm32(const __half* __restrict__ h,
                                                    const int2* __restrict__ em,
                                                    const int* __restrict__ rowptr,
                                                    const float* __restrict__ dis,
                                                    const float* __restrict__ W,
                                                    const float* __restrict__ bias,
                                                    __half* __restrict__ out, int n) {
    __shared__ __align__(16) float sacc[4][32];
    __shared__ __align__(8) int2 sme[4][64];
    int lane = threadIdx.x & 63, wv = threadIdx.x >> 6;
    int c = lane & 15, quarter = lane >> 4;
    const unsigned int* h32 = (const unsigned int*)h;
    float bv = bias[lane];
    int wid = (blockIdx.x * blockDim.x + threadIdx.x) >> 6;
    int nw = (gridDim.x * blockDim.x) >> 6;
    for (int node = wid; node < n; node += nw) {
        int lo = rowptr[node], hi = rowptr[node + 1];
        int deg = hi - lo;
        float2 acc = make_float2(0.0f, 0.0f);
        if (quarter == 0) {
            float2 hv = cvt_pair(h32[(size_t)node * 16 + c]);
            float di = dis[node];
            acc.x = di * hv.x; acc.y = di * hv.y;
        }
        for (int jb = 0; jb < deg; jb += 64) {
            int idx = lo + jb + lane;
            int2 me = (idx < hi) ? em[idx] : make_int2(0, 0);  // w=0 pad
            sme[wv][lane] = me;
            int rem = deg - jb;
#pragma unroll
            for (int g = 0; g < 4; ++g) {
                if (g * 16 < rem) {
#pragma unroll
                    for (int t = 0; t < 4; ++t) {
                        int2 ev = sme[wv][g * 16 + 4 * t + quarter];  // per-quarter bcast
                        float ww = __int_as_float(ev.y);
                        float2 hf = cvt_pair(h32[(size_t)ev.x * 16 + c]);
                        acc.x = fmaf(ww, hf.x, acc.x);
                        acc.y = fmaf(ww, hf.y, acc.y);
                    }
                }
            }
        }
        // cross-quarter reduce (q0+=q2, q1+=q3; then q0+=q1)
        acc.x += __shfl_down(acc.x, 32, 64);
        acc.y += __shfl_down(acc.y, 32, 64);
        acc.x += __shfl_down(acc.x, 16, 64);
        acc.y += __shfl_down(acc.y, 16, 64);
        if (quarter == 0) ((float2*)sacc[wv])[c] = acc;  // floats 2c, 2c+1
        float o = bv;
        const float4* s4 = (const float4*)sacc[wv];
#pragma unroll
        for (int k4 = 0; k4 < 8; ++k4) {
            float4 a4 = s4[k4];
            o = fmaf(a4.x, W[(4 * k4 + 0) * 64 + lane], o);
            o = fmaf(a4.y, W[(4 * k4 + 1) * 64 + lane], o);
            o = fmaf(a4.z, W[(4 * k4 + 2) * 64 + lane], o);
            o = fmaf(a4.w, W[(4 * k4 + 3) * 64 + lane], o);
        }
        o = o / (1.0f + __expf(-o));
        o *= dis[node];
        out[(size_t)node * 64 + lane] = __float2half(o);
    }
}

// pool phase 1: 128-row chunks, segment-flush atomics into acc[G*64]
__global__ void k_pool_partial(const float* __restrict__ h, const int* __restrict__ batch,
                               float* __restrict__ acc, int n) {
    int c = threadIdx.x & 63, r = threadIdx.x >> 6;
    int base = blockIdx.x * 128;
    int end = base + 128; if (end > n) end = n;
    float part = 0.0f;
    int cur = -1;
    for (int i = base + r; i < end; i += 4) {
        int g = batch[i];
        if (g != cur) {
            if (cur >= 0) atomicAdd(&acc[cur * 64 + c], part);
            part = 0.0f;
            cur = g;
        }
        part += h[(size_t)i * 64 + c];
    }
    if (cur >= 0) atomicAdd(&acc[cur * 64 + c], part);
}

// pool phase 2: divide by per-graph count
__global__ void k_pool_final(const float* __restrict__ acc, const int* __restrict__ batch,
                             float* __restrict__ out, int n) {
    int idx = blockIdx.x * blockDim.x + threadIdx.x;   // G*64 threads
    int g = idx >> 6;
    int lo = lower_bound_i(batch, n, g);
    int hi = lower_bound_i(batch, n, g + 1);
    int cnt = hi - lo;
    out[idx] = acc[idx] / (float)(cnt > 0 ? cnt : 1);
}

extern "C" void kernel_launch(void* const* d_in, const int* in_sizes, int n_in,
                              void* d_out, int out_size, void* d_ws, size_t ws_size,
                              hipStream_t stream) {
    const float* x   = (const float*)d_in[0];
    const float* ew  = (const float*)d_in[1];
    const float* W1  = (const float*)d_in[2];
    const float* b1  = (const float*)d_in[3];
    const float* W2  = (const float*)d_in[4];
    const float* b2  = (const float*)d_in[5];
    const float* W3  = (const float*)d_in[6];
    const float* b3  = (const float*)d_in[7];
    const int*   eidx  = (const int*)d_in[8];
    const int*   batch = (const int*)d_in[9];
    float* out = (float*)d_out;

    const int E = in_sizes[1];       // 1,600,000
    const int N = in_sizes[9];       // 100,000 (< 131072: fits 17-bit src pack)
    const int G = 64;
    const int* src = eidx;
    const int* dst = eidx + E;

    // workspace: A/B (fp16 features) double as CSR-build scratch
    // (bedge in A: E*8B == N*64*2B exactly; hcnt/btot in B), both dead by the
    // time features first touch them. C holds the final fp32 layer for pooling.
    char* p = (char*)d_ws;
    __half* A     = (__half*)p;                p += (size_t)N * 64 * sizeof(__half);
    __half* B     = (__half*)p;                p += (size_t)N * 64 * sizeof(__half);
    float* C      = (float*)p;                 p += (size_t)N * 64 * sizeof(float);
    float* dis    = (float*)p;                 p += (size_t)N * sizeof(float);
    int*   rowptr = (int*)p;                   p += (size_t)(N + 1) * sizeof(int);
    int*   bbase  = (int*)p;                   p += (size_t)(NB + 1) * sizeof(int);
    float* acc    = (float*)p;                 p += (size_t)G * 64 * sizeof(float);
    p = (char*)(((uintptr_t)p + 7) & ~(uintptr_t)7);
    int2*  em     = (int2*)p;                  // E entries, 8B

    int2* bedge = (int2*)A;                    // E*8B == N*64*2B
    int*  hcnt  = (int*)B;                     // NB*PBLK*4B = 1MB
    int*  btot  = (int*)B + NB * PBLK;         // NB ints

    const int BT = 256;
    const int FUSED_BLOCKS = 6250;             // 25000 waves x 4 nodes = 100k

    // --- CSR build: LDS counting sort, zero global atomics ---
    k_bhist<<<PBLK, 256, 0, stream>>>(dst, hcnt, E);
    k_bscan<<<NB, 256, 0, stream>>>(hcnt, btot);
    k_bbase<<<1, 256, 0, stream>>>(btot, bbase, rowptr, N, E);
    k_bpart<<<PBLK, 256, 0, stream>>>(src, dst, ew, hcnt, bbase, bedge, E);
    k_bucket<<<NB, 256, 0, stream>>>(bedge, bbase, dis, rowptr, em, N);

    // --- layer 1: hs1 = fp16(dis*x) -> B ; fused agg+mm+silu*dis -> A ---
    // (B's hcnt scratch is dead after k_bpart; A's bedge dead after k_bucket)
    k_scale<<<(N * 32 + BT - 1) / BT, BT, 0, stream>>>(x, dis, (__half*)B, N * 32);
    k_aggmm32<<<FUSED_BLOCKS, BT, 0, stream>>>((__half*)B, em, rowptr, dis, W1, b1, A, N);

    // --- layer 2: fused agg+mm+silu*dis -> B ---
    k_aggmm64<true, __half><<<FUSED_BLOCKS, BT, 0, stream>>>(A, em, rowptr, dis, W2, b2, B, N);

    // --- layer 3: fused agg+mm+silu (raw fp32, for pooling) -> C ---
    k_aggmm64<false, float><<<FUSED_BLOCKS, BT, 0, stream>>>(B, em, rowptr, dis, W3, b3, C, N);

    // --- mean pool ---
    hipMemsetAsync(acc, 0, (size_t)G * 64 * sizeof(float), stream);
    k_pool_partial<<<(N + 127) / 128, BT, 0, stream>>>(C, batch, acc, N);
    k_pool_final<<<(G * 64) / BT, BT, 0, stream>>>(acc, batch, out, N);
}

// Round 13
// 402.427 us; speedup vs baseline: 2.0730x; 1.9372x over previous
//
#include <hip/hip_runtime.h>
#include <hip/hip_fp16.h>
#include <math.h>

// GCN encoder, N=100000, E=1600000, C_IN=32, C_H=C_OUT=64, G=64.
// CSR build via two-level LDS counting sort (NO global atomics).
// em weight = ew*dis[dst]; dis[src] folded into features. FP16 features.
// Fused agg+matmul+bias+SiLU per layer; pair-gather (2 edges/instr via wave
// halves; layer1 4 edges/instr via quarters); edge meta staged in LDS.
// R13: DUAL-NODE per wave — two independent gather streams (2x MLP at the
// fixed ~33% occupancy; launch_bounds must stay (256,4): any min-wave >4
// makes LLVM spill: R11 (256,8)->32 VGPR/718MB, R12 (256,6)->40 VGPR/520MB).
// Epilogue shares W loads across the node pair (halves W traffic for free).

#define NB   256        // dst buckets (512 nodes each; supports N < 131072)
#define PBLK 1024       // partition blocks
#define FIXP_SCALE 1048576.0f   // 2^20
#define FIXP_MASK  ((1ULL << 40) - 1)

__device__ __forceinline__ int lower_bound_i(const int* __restrict__ a, int n, int v) {
    int lo = 0, hi = n;
    while (lo < hi) {
        int m = (lo + hi) >> 1;
        if (a[m] < v) lo = m + 1; else hi = m;
    }
    return lo;
}

// A1: per-block histogram over 256 dst-buckets (LDS atomics only)
__global__ __launch_bounds__(256) void k_bhist(const int* __restrict__ dst,
                                               int* __restrict__ hcnt, int e) {
    __shared__ int hist[NB];
    int tid = threadIdx.x, blk = blockIdx.x;
    hist[tid] = 0;
    __syncthreads();
    int chunk = (e + PBLK - 1) / PBLK;
    int lo = blk * chunk, hi = min(e, lo + chunk);
    for (int i = lo + tid; i < hi; i += 256)
        atomicAdd(&hist[dst[i] >> 9], 1);
    __syncthreads();
    hcnt[tid * PBLK + blk] = hist[tid];   // [bucket][block] layout
}

// A2a: per-bucket exclusive scan across the PBLK block-counts (in place) + totals
__global__ __launch_bounds__(256) void k_bscan(int* __restrict__ hcnt,
                                               int* __restrict__ btot) {
    __shared__ int s[256];
    int b = blockIdx.x, tid = threadIdx.x;
    int* row = hcnt + b * PBLK;
    int a0 = row[4 * tid], a1 = row[4 * tid + 1], a2 = row[4 * tid + 2], a3 = row[4 * tid + 3];
    int tsum = a0 + a1 + a2 + a3;
    s[tid] = tsum;
    __syncthreads();
    for (int off = 1; off < 256; off <<= 1) {
        int t = (tid >= off) ? s[tid - off] : 0;
        __syncthreads();
        s[tid] += t;
        __syncthreads();
    }
    int ex = s[tid] - tsum;
    row[4 * tid] = ex;
    row[4 * tid + 1] = ex + a0;
    row[4 * tid + 2] = ex + a0 + a1;
    row[4 * tid + 3] = ex + a0 + a1 + a2;
    if (tid == 255) btot[b] = s[255];
}

// A2b: scan bucket totals -> bucket_base[NB+1]; also rowptr[n]=e
__global__ __launch_bounds__(256) void k_bbase(const int* __restrict__ btot,
                                               int* __restrict__ bbase,
                                               int* __restrict__ rowptr, int n, int e) {
    __shared__ int s[256];
    int tid = threadIdx.x;
    int v = btot[tid];
    s[tid] = v;
    __syncthreads();
    for (int off = 1; off < 256; off <<= 1) {
        int t = (tid >= off) ? s[tid - off] : 0;
        __syncthreads();
        s[tid] += t;
        __syncthreads();
    }
    bbase[tid] = s[tid] - v;
    if (tid == 255) bbase[NB] = s[255];   // == e
    if (tid == 0) rowptr[n] = e;
}

// A3: partition edges into buckets; pos from LDS cursor (no global atomics)
__global__ __launch_bounds__(256) void k_bpart(const int* __restrict__ src,
                                               const int* __restrict__ dst,
                                               const float* __restrict__ ew,
                                               const int* __restrict__ hcnt,
                                               const int* __restrict__ bbase,
                                               int2* __restrict__ bedge, int e) {
    __shared__ int cur[NB];
    int tid = threadIdx.x, blk = blockIdx.x;
    cur[tid] = bbase[tid] + hcnt[tid * PBLK + blk];
    __syncthreads();
    int chunk = (e + PBLK - 1) / PBLK;
    int lo = blk * chunk, hi = min(e, lo + chunk);
    for (int i = lo + tid; i < hi; i += 256) {
        int d = dst[i];
        int pos = atomicAdd(&cur[d >> 9], 1);            // LDS atomic
        bedge[pos] = make_int2(src[i] | ((d & 511) << 17), __float_as_int(ew[i]));
    }
}

// B: per-bucket (512 nodes): LDS packed cnt + fixp sum(ew) -> dis, rowptr,
// then scatter (src, ew*dis[d]) grouped per node into em. No global atomics.
__global__ __launch_bounds__(256) void k_bucket(const int2* __restrict__ bedge,
                                                const int* __restrict__ bbase,
                                                float* __restrict__ dis,
                                                int* __restrict__ rowptr,
                                                int2* __restrict__ em, int n) {
    __shared__ unsigned long long pk[512];
    __shared__ int cnt[512];
    __shared__ int scn[512];
    __shared__ float sdis[512];
    __shared__ int cur[512];
    int b = blockIdx.x, tid = threadIdx.x;
    int e0 = bbase[b], e1 = bbase[b + 1];
    pk[tid] = 0ULL; pk[tid + 256] = 0ULL;
    __syncthreads();
    for (int i = e0 + tid; i < e1; i += 256) {
        int2 v = bedge[i];
        int dlo = (v.x >> 17) & 511;
        unsigned long long p =
            (1ULL << 40) | (unsigned long long)(__int_as_float(v.y) * FIXP_SCALE);
        atomicAdd(&pk[dlo], p);                          // LDS atomic
    }
    __syncthreads();
#pragma unroll
    for (int k = 0; k < 2; ++k) {
        int i = tid + k * 256;
        unsigned long long v = pk[i];
        int c = (int)(v >> 40);
        cnt[i] = c; scn[i] = c;
        sdis[i] = rsqrtf(1.0f + (float)(v & FIXP_MASK) * (1.0f / FIXP_SCALE));
    }
    __syncthreads();
    // 512-entry inclusive scan, 2 elems/thread, read-all-then-write-all
    for (int off = 1; off < 512; off <<= 1) {
        int i0 = tid, i1 = tid + 256;
        int v0 = (i0 >= off) ? scn[i0 - off] : 0;
        int v1 = (i1 >= off) ? scn[i1 - off] : 0;
        __syncthreads();
        scn[i0] += v0; scn[i1] += v1;
        __syncthreads();
    }
#pragma unroll
    for (int k = 0; k < 2; ++k) {
        int i = tid + k * 256;
        int rb = e0 + scn[i] - cnt[i];                   // exclusive
        cur[i] = rb;
        int node = (b << 9) + i;
        if (node < n) { rowptr[node] = rb; dis[node] = sdis[i]; }
    }
    __syncthreads();
    for (int i = e0 + tid; i < e1; i += 256) {
        int2 v = bedge[i];
        int dlo = (v.x >> 17) & 511;
        int pos = atomicAdd(&cur[dlo], 1);               // LDS atomic
        float w = __int_as_float(v.y) * sdis[dlo];
        em[pos] = make_int2(v.x & 0x1FFFF, __float_as_int(w));
    }
}

// hs = fp16(dis * x)  (layer-1 feature pre-scale, 32 channels)
__global__ void k_scale(const float* __restrict__ x, const float* __restrict__ dis,
                        __half* __restrict__ hs, int total) {
    int idx = blockIdx.x * blockDim.x + threadIdx.x;
    if (idx < total) hs[idx] = __float2half(x[idx] * dis[idx >> 5]);
}

__device__ __forceinline__ float2 cvt_pair(unsigned int u) {
    __half2 h2 = *(__half2*)&u;
    return __half22float2(h2);
}

// Fused agg + 64x64 matvec + bias + SiLU (+dis prescale). FP16 features.
// DUAL-NODE: each wave runs two independent node streams (n0=2k, n1=2k+1);
// all stream guards are wave-uniform (scalar branches). Pair-gather within
// each stream via wave halves. Epilogue shares W loads across the pair.
template <bool SCALE, typename OUT>
__global__ __launch_bounds__(256, 4) void k_aggmm64(const __half* __restrict__ h,
                                                    const int2* __restrict__ em,
                                                    const int* __restrict__ rowptr,
                                                    const float* __restrict__ dis,
                                                    const float* __restrict__ W,
                                                    const float* __restrict__ bias,
                                                    OUT* __restrict__ out, int n) {
    __shared__ __align__(16) float sacc[4][2][64];
    __shared__ __align__(8) int2 sme[4][2][64];
    int lane = threadIdx.x & 63, wv = threadIdx.x >> 6;
    int c = lane & 31, half = lane >> 5;
    const unsigned int* h32 = (const unsigned int*)h;
    float bv = bias[lane];
    int wid = (blockIdx.x * blockDim.x + threadIdx.x) >> 6;
    int nw = (gridDim.x * blockDim.x) >> 6;
    int npair = (n + 1) >> 1;
    for (int pr = wid; pr < npair; pr += nw) {
        int n0 = 2 * pr, n1 = 2 * pr + 1;
        bool has1 = (n1 < n);
        int lo0 = rowptr[n0], hi0 = rowptr[n0 + 1];
        int lo1 = has1 ? rowptr[n1] : 0, hi1 = has1 ? rowptr[n1 + 1] : 0;
        int deg0 = hi0 - lo0, deg1 = hi1 - lo1;
        int degm = max(deg0, deg1);
        float2 acc0 = make_float2(0.0f, 0.0f), acc1 = make_float2(0.0f, 0.0f);
        if (half == 0) {
            float2 hv0 = cvt_pair(h32[(size_t)n0 * 32 + c]);
            float d0 = dis[n0];
            acc0.x = d0 * hv0.x; acc0.y = d0 * hv0.y;    // di^2*h = di*hs
            if (has1) {
                float2 hv1 = cvt_pair(h32[(size_t)n1 * 32 + c]);
                float d1 = dis[n1];
                acc1.x = d1 * hv1.x; acc1.y = d1 * hv1.y;
            }
        }
        for (int jb = 0; jb < degm; jb += 64) {
            int2 me0 = (jb + lane < deg0) ? em[lo0 + jb + lane] : make_int2(0, 0);
            int2 me1 = (jb + lane < deg1) ? em[lo1 + jb + lane] : make_int2(0, 0);
            sme[wv][0][lane] = me0;
            sme[wv][1][lane] = me1;
            int remm = degm - jb;
#pragma unroll
            for (int g = 0; g < 4; ++g) {
                if (g * 16 < remm) {
#pragma unroll
                    for (int t = 0; t < 8; ++t) {
                        int ei = g * 16 + 2 * t + half;
                        int2 e0 = sme[wv][0][ei];        // per-half bcast
                        int2 e1 = sme[wv][1][ei];
                        float w0 = __int_as_float(e0.y);
                        float w1 = __int_as_float(e1.y);
                        float2 f0 = cvt_pair(h32[(size_t)e0.x * 32 + c]);
                        float2 f1 = cvt_pair(h32[(size_t)e1.x * 32 + c]);
                        acc0.x = fmaf(w0, f0.x, acc0.x);
                        acc0.y = fmaf(w0, f0.y, acc0.y);
                        acc1.x = fmaf(w1, f1.x, acc1.x);
                        acc1.y = fmaf(w1, f1.y, acc1.y);
                    }
                }
            }
        }
        // cross-half reduce, channel-pair layout into sacc
        acc0.x += __shfl_down(acc0.x, 32, 64);
        acc0.y += __shfl_down(acc0.y, 32, 64);
        acc1.x += __shfl_down(acc1.x, 32, 64);
        acc1.y += __shfl_down(acc1.y, 32, 64);
        if (half == 0) {
            ((float2*)sacc[wv][0])[c] = acc0;            // floats 2c, 2c+1
            ((float2*)sacc[wv][1])[c] = acc1;
        }
        float o0 = bv, o1 = bv;
        const float4* s40 = (const float4*)sacc[wv][0];
        const float4* s41 = (const float4*)sacc[wv][1];
#pragma unroll
        for (int k4 = 0; k4 < 16; ++k4) {
            float w0 = W[(4 * k4 + 0) * 64 + lane];
            float w1 = W[(4 * k4 + 1) * 64 + lane];
            float w2 = W[(4 * k4 + 2) * 64 + lane];
            float w3 = W[(4 * k4 + 3) * 64 + lane];
            float4 a0 = s40[k4];                 // same addr all lanes: broadcast
            float4 a1 = s41[k4];
            o0 = fmaf(a0.x, w0, o0); o1 = fmaf(a1.x, w0, o1);
            o0 = fmaf(a0.y, w1, o0); o1 = fmaf(a1.y, w1, o1);
            o0 = fmaf(a0.z, w2, o0); o1 = fmaf(a1.z, w2, o1);
            o0 = fmaf(a0.w, w3, o0); o1 = fmaf(a1.w, w3, o1);
        }
        o0 = o0 / (1.0f + __expf(-o0));
        o1 = o1 / (1.0f + __expf(-o1));
        if (SCALE) {
            o0 *= dis[n0];
            if (has1) o1 *= dis[n1];
        }
        if (sizeof(OUT) == 2) {
            ((__half*)out)[(size_t)n0 * 64 + lane] = __float2half(o0);
            if (has1) ((__half*)out)[(size_t)n1 * 64 + lane] = __float2half(o1);
        } else {
            ((float*)out)[(size_t)n0 * 64 + lane] = o0;
            if (has1) ((float*)out)[(size_t)n1 * 64 + lane] = o1;
        }
    }
}

// Fused layer-1 (32-ch fp16 input), DUAL-NODE: quarter-split gather
// (4 edges/instr per stream), shared-W 32x64 epilogue.
__global__ __launch_bounds__(256, 4) void k_aggmm32(const __half* __restrict__ h,
                                                    const int2* __restrict__ em,
                                                    const int* __restrict__ rowptr,
                                                    const float* __restrict__ dis,
                                                    const float* __restrict__ W,
                                                    const float* __restrict__ bias,
                                                    __half* __restrict__ out, int n) {
    __shared__ __align__(16) float sacc[4][2][32];
    __shared__ __align__(8) int2 sme[4][2][64];
    int lane = threadIdx.x & 63, wv = threadIdx.x >> 6;
    int c = lane & 15, quarter = lane >> 4;
    const unsigned int* h32 = (const unsigned int*)h;
    float bv = bias[lane];
    int wid = (blockIdx.x * blockDim.x + threadIdx.x) >> 6;
    int nw = (gridDim.x * blockDim.x) >> 6;
    int npair = (n + 1) >> 1;
    for (int pr = wid; pr < npair; pr += nw) {
        int n0 = 2 * pr, n1 = 2 * pr + 1;
        bool has1 = (n1 < n);
        int lo0 = rowptr[n0], hi0 = rowptr[n0 + 1];
        int lo1 = has1 ? rowptr[n1] : 0, hi1 = has1 ? rowptr[n1 + 1] : 0;
        int deg0 = hi0 - lo0, deg1 = hi1 - lo1;
        int degm = max(deg0, deg1);
        float2 acc0 = make_float2(0.0f, 0.0f), acc1 = make_float2(0.0f, 0.0f);
        if (quarter == 0) {
            float2 hv0 = cvt_pair(h32[(size_t)n0 * 16 + c]);
            float d0 = dis[n0];
            acc0.x = d0 * hv0.x; acc0.y = d0 * hv0.y;
            if (has1) {
                float2 hv1 = cvt_pair(h32[(size_t)n1 * 16 + c]);
                float d1 = dis[n1];
                acc1.x = d1 * hv1.x; acc1.y = d1 * hv1.y;
            }
        }
        for (int jb = 0; jb < degm; jb += 64) {
            int2 me0 = (jb + lane < deg0) ? em[lo0 + jb + lane] : make_int2(0, 0);
            int2 me1 = (jb + lane < deg1) ? em[lo1 + jb + lane] : make_int2(0, 0);
            sme[wv][0][lane] = me0;
            sme[wv][1][lane] = me1;
            int remm = degm - jb;
#pragma unroll
            for (int g = 0; g < 4; ++g) {
                if (g * 16 < remm) {
#pragma unroll
                    for (int t = 0; t < 4; ++t) {
                        int ei = g * 16 + 4 * t + quarter;
                        int2 e0 = sme[wv][0][ei];        // per-quarter bcast
                        int2 e1 = sme[wv][1][ei];
                        float w0 = __int_as_float(e0.y);
                        float w1 = __int_as_float(e1.y);
                        float2 f0 = cvt_pair(h32[(size_t)e0.x * 16 + c]);
                        float2 f1 = cvt_pair(h32[(size_t)e1.x * 16 + c]);
                        acc0.x = fmaf(w0, f0.x, acc0.x);
                        acc0.y = fmaf(w0, f0.y, acc0.y);
                        acc1.x = fmaf(w1, f1.x, acc1.x);
                        acc1.y = fmaf(w1, f1.y, acc1.y);
                    }
                }
            }
        }
        // cross-quarter reduce (q0+=q2, q1+=q3; then q0+=q1)
        acc0.x += __shfl_down(acc0.x, 32, 64);
        acc0.y += __shfl_down(acc0.y, 32, 64);
        acc1.x += __shfl_down(acc1.x, 32, 64);
        acc1.y += __shfl_down(acc1.y, 32, 64);
        acc0.x += __shfl_down(acc0.x, 16, 64);
        acc0.y += __shfl_down(acc0.y, 16, 64);
        acc1.x += __shfl_down(acc1.x, 16, 64);
        acc1.y += __shfl_down(acc1.y, 16, 64);
        if (quarter == 0) {
            ((float2*)sacc[wv][0])[c] = acc0;            // floats 2c, 2c+1
            ((float2*)sacc[wv][1])[c] = acc1;
        }
        float o0 = bv, o1 = bv;
        const float4* s40 = (const float4*)sacc[wv][0];
        const float4* s41 = (const float4*)sacc[wv][1];
#pragma unroll
        for (int k4 = 0; k4 < 8; ++k4) {
            float w0 = W[(4 * k4 + 0) * 64 + lane];
            float w1 = W[(4 * k4 + 1) * 64 + lane];
            float w2 = W[(4 * k4 + 2) * 64 + lane];
            float w3 = W[(4 * k4 + 3) * 64 + lane];
            float4 a0 = s40[k4];
            float4 a1 = s41[k4];
            o0 = fmaf(a0.x, w0, o0); o1 = fmaf(a1.x, w0, o1);
            o0 = fmaf(a0.y, w1, o0); o1 = fmaf(a1.y, w1, o1);
            o0 = fmaf(a0.z, w2, o0); o1 = fmaf(a1.z, w2, o1);
            o0 = fmaf(a0.w, w3, o0); o1 = fmaf(a1.w, w3, o1);
        }
        o0 = o0 / (1.0f + __expf(-o0));
        o1 = o1 / (1.0f + __expf(-o1));
        o0 *= dis[n0];
        out[(size_t)n0 * 64 + lane] = __float2half(o0);
        if (has1) {
            o1 *= dis[n1];
            out[(size_t)n1 * 64 + lane] = __float2half(o1);
        }
    }
}

// pool phase 1: 128-row chunks, segment-flush atomics into acc[G*64]
__global__ void k_pool_partial(const float* __restrict__ h, const int* __restrict__ batch,
                               float* __restrict__ acc, int n) {
    int c = threadIdx.x & 63, r = threadIdx.x >> 6;
    int base = blockIdx.x * 128;
    int end = base + 128; if (end > n) end = n;
    float part = 0.0f;
    int cur = -1;
    for (int i = base + r; i < end; i += 4) {
        int g = batch[i];
        if (g != cur) {
            if (cur >= 0) atomicAdd(&acc[cur * 64 + c], part);
            part = 0.0f;
            cur = g;
        }
        part += h[(size_t)i * 64 + c];
    }
    if (cur >= 0) atomicAdd(&acc[cur * 64 + c], part);
}

// pool phase 2: divide by per-graph count
__global__ void k_pool_final(const float* __restrict__ acc, const int* __restrict__ batch,
                             float* __restrict__ out, int n) {
    int idx = blockIdx.x * blockDim.x + threadIdx.x;   // G*64 threads
    int g = idx >> 6;
    int lo = lower_bound_i(batch, n, g);
    int hi = lower_bound_i(batch, n, g + 1);
    int cnt = hi - lo;
    out[idx] = acc[idx] / (float)(cnt > 0 ? cnt : 1);
}

extern "C" void kernel_launch(void* const* d_in, const int* in_sizes, int n_in,
                              void* d_out, int out_size, void* d_ws, size_t ws_size,
                              hipStream_t stream) {
    const float* x   = (const float*)d_in[0];
    const float* ew  = (const float*)d_in[1];
    const float* W1  = (const float*)d_in[2];
    const float* b1  = (const float*)d_in[3];
    const float* W2  = (const float*)d_in[4];
    const float* b2  = (const float*)d_in[5];
    const float* W3  = (const float*)d_in[6];
    const float* b3  = (const float*)d_in[7];
    const int*   eidx  = (const int*)d_in[8];
    const int*   batch = (const int*)d_in[9];
    float* out = (float*)d_out;

    const int E = in_sizes[1];       // 1,600,000
    const int N = in_sizes[9];       // 100,000 (< 131072: fits 17-bit src pack)
    const int G = 64;
    const int* src = eidx;
    const int* dst = eidx + E;

    // workspace: A/B (fp16 features) double as CSR-build scratch
    // (bedge in A: E*8B == N*64*2B exactly; hcnt/btot in B), both dead by the
    // time features first touch them. C holds the final fp32 layer for pooling.
    char* p = (char*)d_ws;
    __half* A     = (__half*)p;                p += (size_t)N * 64 * sizeof(__half);
    __half* B     = (__half*)p;                p += (size_t)N * 64 * sizeof(__half);
    float* C      = (float*)p;                 p += (size_t)N * 64 * sizeof(float);
    float* dis    = (float*)p;                 p += (size_t)N * sizeof(float);
    int*   rowptr = (int*)p;                   p += (size_t)(N + 1) * sizeof(int);
    int*   bbase  = (int*)p;                   p += (size_t)(NB + 1) * sizeof(int);
    float* acc    = (float*)p;                 p += (size_t)G * 64 * sizeof(float);
    p = (char*)(((uintptr_t)p + 7) & ~(uintptr_t)7);
    int2*  em     = (int2*)p;                  // E entries, 8B

    int2* bedge = (int2*)A;                    // E*8B == N*64*2B
    int*  hcnt  = (int*)B;                     // NB*PBLK*4B = 1MB
    int*  btot  = (int*)B + NB * PBLK;         // NB ints

    const int BT = 256;
    const int FUSED_BLOCKS = 3125;             // 12500 waves x 4 pairs = 100k

    // --- CSR build: LDS counting sort, zero global atomics ---
    k_bhist<<<PBLK, 256, 0, stream>>>(dst, hcnt, E);
    k_bscan<<<NB, 256, 0, stream>>>(hcnt, btot);
    k_bbase<<<1, 256, 0, stream>>>(btot, bbase, rowptr, N, E);
    k_bpart<<<PBLK, 256, 0, stream>>>(src, dst, ew, hcnt, bbase, bedge, E);
    k_bucket<<<NB, 256, 0, stream>>>(bedge, bbase, dis, rowptr, em, N);

    // --- layer 1: hs1 = fp16(dis*x) -> B ; fused agg+mm+silu*dis -> A ---
    // (B's hcnt scratch is dead after k_bpart; A's bedge dead after k_bucket)
    k_scale<<<(N * 32 + BT - 1) / BT, BT, 0, stream>>>(x, dis, (__half*)B, N * 32);
    k_aggmm32<<<FUSED_BLOCKS, BT, 0, stream>>>((__half*)B, em, rowptr, dis, W1, b1, A, N);

    // --- layer 2: fused agg+mm+silu*dis -> B ---
    k_aggmm64<true, __half><<<FUSED_BLOCKS, BT, 0, stream>>>(A, em, rowptr, dis, W2, b2, B, N);

    // --- layer 3: fused agg+mm+silu (raw fp32, for pooling) -> C ---
    k_aggmm64<false, float><<<FUSED_BLOCKS, BT, 0, stream>>>(B, em, rowptr, dis, W3, b3, C, N);

    // --- mean pool ---
    hipMemsetAsync(acc, 0, (size_t)G * 64 * sizeof(float), stream);
    k_pool_partial<<<(N + 127) / 128, BT, 0, stream>>>(C, batch, acc, N);
    k_pool_final<<<(G * 64) / BT, BT, 0, stream>>>(acc, batch, out, N);
}

// Round 14
// 358.648 us; speedup vs baseline: 2.3261x; 1.1221x over previous
//
#include <hip/hip_runtime.h>
#include <hip/hip_fp16.h>
#include <math.h>

// GCN encoder, N=100000, E=1600000, C_IN=32, C_H=C_OUT=64, G=64.
// CSR build via two-level LDS counting sort (NO global atomics).
// em weight = ew*dis[dst]; dis[src] folded into features. FP16 features.
// Fused agg+matmul+bias+SiLU per layer. R14: WIDE GATHER — uint2 (8B) per
// lane: 16 lanes cover a 64-ch fp16 row -> 4 edges per gather instruction
// (layer1: 8 lanes/row -> 8 edges/instr). Halves vmem instructions per edge
// and doubles in-flight bytes per vmcnt slot (latency-bound regime).
// launch_bounds stays (256,4): min-waves>4 makes LLVM spill (R11/R12).
// Failed attempts (do not retry): R10 batched epilogue (+LDS round-trips,
// W reloads were not the bottleneck), R11 (256,8)/R12 (256,6) spill,
// R13 dual-node (pad-to-max wasted gathers + spill).

#define NB   256        // dst buckets (512 nodes each; supports N < 131072)
#define PBLK 1024       // partition blocks
#define FIXP_SCALE 1048576.0f   // 2^20
#define FIXP_MASK  ((1ULL << 40) - 1)

__device__ __forceinline__ int lower_bound_i(const int* __restrict__ a, int n, int v) {
    int lo = 0, hi = n;
    while (lo < hi) {
        int m = (lo + hi) >> 1;
        if (a[m] < v) lo = m + 1; else hi = m;
    }
    return lo;
}

// A1: per-block histogram over 256 dst-buckets (LDS atomics only)
__global__ __launch_bounds__(256) void k_bhist(const int* __restrict__ dst,
                                               int* __restrict__ hcnt, int e) {
    __shared__ int hist[NB];
    int tid = threadIdx.x, blk = blockIdx.x;
    hist[tid] = 0;
    __syncthreads();
    int chunk = (e + PBLK - 1) / PBLK;
    int lo = blk * chunk, hi = min(e, lo + chunk);
    for (int i = lo + tid; i < hi; i += 256)
        atomicAdd(&hist[dst[i] >> 9], 1);
    __syncthreads();
    hcnt[tid * PBLK + blk] = hist[tid];   // [bucket][block] layout
}

// A2a: per-bucket exclusive scan across the PBLK block-counts (in place) + totals
__global__ __launch_bounds__(256) void k_bscan(int* __restrict__ hcnt,
                                               int* __restrict__ btot) {
    __shared__ int s[256];
    int b = blockIdx.x, tid = threadIdx.x;
    int* row = hcnt + b * PBLK;
    int a0 = row[4 * tid], a1 = row[4 * tid + 1], a2 = row[4 * tid + 2], a3 = row[4 * tid + 3];
    int tsum = a0 + a1 + a2 + a3;
    s[tid] = tsum;
    __syncthreads();
    for (int off = 1; off < 256; off <<= 1) {
        int t = (tid >= off) ? s[tid - off] : 0;
        __syncthreads();
        s[tid] += t;
        __syncthreads();
    }
    int ex = s[tid] - tsum;
    row[4 * tid] = ex;
    row[4 * tid + 1] = ex + a0;
    row[4 * tid + 2] = ex + a0 + a1;
    row[4 * tid + 3] = ex + a0 + a1 + a2;
    if (tid == 255) btot[b] = s[255];
}

// A2b: scan bucket totals -> bucket_base[NB+1]; also rowptr[n]=e
__global__ __launch_bounds__(256) void k_bbase(const int* __restrict__ btot,
                                               int* __restrict__ bbase,
                                               int* __restrict__ rowptr, int n, int e) {
    __shared__ int s[256];
    int tid = threadIdx.x;
    int v = btot[tid];
    s[tid] = v;
    __syncthreads();
    for (int off = 1; off < 256; off <<= 1) {
        int t = (tid >= off) ? s[tid - off] : 0;
        __syncthreads();
        s[tid] += t;
        __syncthreads();
    }
    bbase[tid] = s[tid] - v;
    if (tid == 255) bbase[NB] = s[255];   // == e
    if (tid == 0) rowptr[n] = e;
}

// A3: partition edges into buckets; pos from LDS cursor (no global atomics)
__global__ __launch_bounds__(256) void k_bpart(const int* __restrict__ src,
                                               const int* __restrict__ dst,
                                               const float* __restrict__ ew,
                                               const int* __restrict__ hcnt,
                                               const int* __restrict__ bbase,
                                               int2* __restrict__ bedge, int e) {
    __shared__ int cur[NB];
    int tid = threadIdx.x, blk = blockIdx.x;
    cur[tid] = bbase[tid] + hcnt[tid * PBLK + blk];
    __syncthreads();
    int chunk = (e + PBLK - 1) / PBLK;
    int lo = blk * chunk, hi = min(e, lo + chunk);
    for (int i = lo + tid; i < hi; i += 256) {
        int d = dst[i];
        int pos = atomicAdd(&cur[d >> 9], 1);            // LDS atomic
        bedge[pos] = make_int2(src[i] | ((d & 511) << 17), __float_as_int(ew[i]));
    }
}

// B: per-bucket (512 nodes): LDS packed cnt + fixp sum(ew) -> dis, rowptr,
// then scatter (src, ew*dis[d]) grouped per node into em. No global atomics.
__global__ __launch_bounds__(256) void k_bucket(const int2* __restrict__ bedge,
                                                const int* __restrict__ bbase,
                                                float* __restrict__ dis,
                                                int* __restrict__ rowptr,
                                                int2* __restrict__ em, int n) {
    __shared__ unsigned long long pk[512];
    __shared__ int cnt[512];
    __shared__ int scn[512];
    __shared__ float sdis[512];
    __shared__ int cur[512];
    int b = blockIdx.x, tid = threadIdx.x;
    int e0 = bbase[b], e1 = bbase[b + 1];
    pk[tid] = 0ULL; pk[tid + 256] = 0ULL;
    __syncthreads();
    for (int i = e0 + tid; i < e1; i += 256) {
        int2 v = bedge[i];
        int dlo = (v.x >> 17) & 511;
        unsigned long long p =
            (1ULL << 40) | (unsigned long long)(__int_as_float(v.y) * FIXP_SCALE);
        atomicAdd(&pk[dlo], p);                          // LDS atomic
    }
    __syncthreads();
#pragma unroll
    for (int k = 0; k < 2; ++k) {
        int i = tid + k * 256;
        unsigned long long v = pk[i];
        int c = (int)(v >> 40);
        cnt[i] = c; scn[i] = c;
        sdis[i] = rsqrtf(1.0f + (float)(v & FIXP_MASK) * (1.0f / FIXP_SCALE));
    }
    __syncthreads();
    // 512-entry inclusive scan, 2 elems/thread, read-all-then-write-all
    for (int off = 1; off < 512; off <<= 1) {
        int i0 = tid, i1 = tid + 256;
        int v0 = (i0 >= off) ? scn[i0 - off] : 0;
        int v1 = (i1 >= off) ? scn[i1 - off] : 0;
        __syncthreads();
        scn[i0] += v0; scn[i1] += v1;
        __syncthreads();
    }
#pragma unroll
    for (int k = 0; k < 2; ++k) {
        int i = tid + k * 256;
        int rb = e0 + scn[i] - cnt[i];                   // exclusive
        cur[i] = rb;
        int node = (b << 9) + i;
        if (node < n) { rowptr[node] = rb; dis[node] = sdis[i]; }
    }
    __syncthreads();
    for (int i = e0 + tid; i < e1; i += 256) {
        int2 v = bedge[i];
        int dlo = (v.x >> 17) & 511;
        int pos = atomicAdd(&cur[dlo], 1);               // LDS atomic
        float w = __int_as_float(v.y) * sdis[dlo];
        em[pos] = make_int2(v.x & 0x1FFFF, __float_as_int(w));
    }
}

// hs = fp16(dis * x)  (layer-1 feature pre-scale, 32 channels)
__global__ void k_scale(const float* __restrict__ x, const float* __restrict__ dis,
                        __half* __restrict__ hs, int total) {
    int idx = blockIdx.x * blockDim.x + threadIdx.x;
    if (idx < total) hs[idx] = __float2half(x[idx] * dis[idx >> 5]);
}

__device__ __forceinline__ float2 cvt_pair(unsigned int u) {
    __half2 h2 = *(__half2*)&u;
    return __half22float2(h2);
}

// Fused agg + 64x64 matvec + bias + SiLU (+dis prescale). FP16 features.
// Wide gather: lane = channel-quad c8 (uint2 = 4 fp16), 16 lanes/row, wave
// groups (grp=lane>>4) take edges mod 4 -> 4 edges per gather instruction.
// Edge meta staged in LDS, 4-way broadcast ds_read.
template <bool SCALE, typename OUT>
__global__ __launch_bounds__(256, 4) void k_aggmm64(const __half* __restrict__ h,
                                                    const int2* __restrict__ em,
                                                    const int* __restrict__ rowptr,
                                                    const float* __restrict__ dis,
                                                    const float* __restrict__ W,
                                                    const float* __restrict__ bias,
                                                    OUT* __restrict__ out, int n) {
    __shared__ __align__(16) float sacc[4][64];
    __shared__ __align__(8) int2 sme[4][64];
    int lane = threadIdx.x & 63, wv = threadIdx.x >> 6;
    int c8 = lane & 15, grp = lane >> 4;     // channel-quad, edge-group
    const uint2* h64 = (const uint2*)h;      // row = 16 x 8B = 128B
    float bv = bias[lane];
    int wid = (blockIdx.x * blockDim.x + threadIdx.x) >> 6;
    int nw = (gridDim.x * blockDim.x) >> 6;
    for (int node = wid; node < n; node += nw) {
        int lo = rowptr[node], hi = rowptr[node + 1];
        int deg = hi - lo;
        float4 acc = make_float4(0.0f, 0.0f, 0.0f, 0.0f);
        if (grp == 0) {
            uint2 hv = h64[(size_t)node * 16 + c8];
            float2 p0 = cvt_pair(hv.x), p1 = cvt_pair(hv.y);
            float di = dis[node];
            acc.x = di * p0.x; acc.y = di * p0.y;        // di^2*h = di*hs
            acc.z = di * p1.x; acc.w = di * p1.y;
        }
        for (int jb = 0; jb < deg; jb += 64) {
            int idx = lo + jb + lane;
            int2 me = (idx < hi) ? em[idx] : make_int2(0, 0);  // w=0 pad
            sme[wv][lane] = me;
            int rem = deg - jb;
#pragma unroll
            for (int g = 0; g < 4; ++g) {
                if (g * 16 < rem) {
#pragma unroll
                    for (int t = 0; t < 4; ++t) {
                        int2 ev = sme[wv][g * 16 + 4 * t + grp];  // per-group bcast
                        float ww = __int_as_float(ev.y);
                        uint2 hf = h64[(size_t)ev.x * 16 + c8];
                        float2 f0 = cvt_pair(hf.x), f1 = cvt_pair(hf.y);
                        acc.x = fmaf(ww, f0.x, acc.x);
                        acc.y = fmaf(ww, f0.y, acc.y);
                        acc.z = fmaf(ww, f1.x, acc.z);
                        acc.w = fmaf(ww, f1.y, acc.w);
                    }
                }
            }
        }
        // reduce across the 4 edge-groups (delta 32, then 16)
        acc.x += __shfl_down(acc.x, 32, 64);
        acc.y += __shfl_down(acc.y, 32, 64);
        acc.z += __shfl_down(acc.z, 32, 64);
        acc.w += __shfl_down(acc.w, 32, 64);
        acc.x += __shfl_down(acc.x, 16, 64);
        acc.y += __shfl_down(acc.y, 16, 64);
        acc.z += __shfl_down(acc.z, 16, 64);
        acc.w += __shfl_down(acc.w, 16, 64);
        if (grp == 0) ((float4*)sacc[wv])[c8] = acc;     // channels 4c8..4c8+3
        float o = bv;
        const float4* s4 = (const float4*)sacc[wv];
#pragma unroll
        for (int k4 = 0; k4 < 16; ++k4) {
            float4 a4 = s4[k4];                 // same addr all lanes: broadcast
            o = fmaf(a4.x, W[(4 * k4 + 0) * 64 + lane], o);
            o = fmaf(a4.y, W[(4 * k4 + 1) * 64 + lane], o);
            o = fmaf(a4.z, W[(4 * k4 + 2) * 64 + lane], o);
            o = fmaf(a4.w, W[(4 * k4 + 3) * 64 + lane], o);
        }
        o = o / (1.0f + __expf(-o));
        if (SCALE) o *= dis[node];
        if (sizeof(OUT) == 2) {
            ((__half*)out)[(size_t)node * 64 + lane] = __float2half(o);
        } else {
            ((float*)out)[(size_t)node * 64 + lane] = o;
        }
    }
}

// Fused layer-1 (32-ch fp16 input): 8 lanes/row (uint2 = 4 fp16 each), wave
// groups (grp=lane>>3) take edges mod 8 -> 8 edges per gather instruction.
__global__ __launch_bounds__(256, 4) void k_aggmm32(const __half* __restrict__ h,
                                                    const int2* __restrict__ em,
                                                    const int* __restrict__ rowptr,
                                                    const float* __restrict__ dis,
                                                    const float* __restrict__ W,
                                                    const float* __restrict__ bias,
                                                    __half* __restrict__ out, int n) {
    __shared__ __align__(16) float sacc[4][32];
    __shared__ __align__(8) int2 sme[4][64];
    int lane = threadIdx.x & 63, wv = threadIdx.x >> 6;
    int c8 = lane & 7, grp = lane >> 3;      // channel-quad, edge-group (8)
    const uint2* h64 = (const uint2*)h;      // row = 8 x 8B = 64B
    float bv = bias[lane];
    int wid = (blockIdx.x * blockDim.x + threadIdx.x) >> 6;
    int nw = (gridDim.x * blockDim.x) >> 6;
    for (int node = wid; node < n; node += nw) {
        int lo = rowptr[node], hi = rowptr[node + 1];
        int deg = hi - lo;
        float4 acc = make_float4(0.0f, 0.0f, 0.0f, 0.0f);
        if (grp == 0) {
            uint2 hv = h64[(size_t)node * 8 + c8];
            float2 p0 = cvt_pair(hv.x), p1 = cvt_pair(hv.y);
            float di = dis[node];
            acc.x = di * p0.x; acc.y = di * p0.y;
            acc.z = di * p1.x; acc.w = di * p1.y;
        }
        for (int jb = 0; jb < deg; jb += 64) {
            int idx = lo + jb + lane;
            int2 me = (idx < hi) ? em[idx] : make_int2(0, 0);  // w=0 pad
            sme[wv][lane] = me;
            int rem = deg - jb;
#pragma unroll
            for (int g = 0; g < 4; ++g) {
                if (g * 16 < rem) {
#pragma unroll
                    for (int t = 0; t < 2; ++t) {
                        int2 ev = sme[wv][g * 16 + 8 * t + grp];  // per-group bcast
                        float ww = __int_as_float(ev.y);
                        uint2 hf = h64[(size_t)ev.x * 8 + c8];
                        float2 f0 = cvt_pair(hf.x), f1 = cvt_pair(hf.y);
                        acc.x = fmaf(ww, f0.x, acc.x);
                        acc.y = fmaf(ww, f0.y, acc.y);
                        acc.z = fmaf(ww, f1.x, acc.z);
                        acc.w = fmaf(ww, f1.y, acc.w);
                    }
                }
            }
        }
        // reduce across the 8 edge-groups (delta 32, 16, 8)
        acc.x += __shfl_down(acc.x, 32, 64);
        acc.y += __shfl_down(acc.y, 32, 64);
        acc.z += __shfl_down(acc.z, 32, 64);
        acc.w += __shfl_down(acc.w, 32, 64);
        acc.x += __shfl_down(acc.x, 16, 64);
        acc.y += __shfl_down(acc.y, 16, 64);
        acc.z += __shfl_down(acc.z, 16, 64);
        acc.w += __shfl_down(acc.w, 16, 64);
        acc.x += __shfl_down(acc.x, 8, 64);
        acc.y += __shfl_down(acc.y, 8, 64);
        acc.z += __shfl_down(acc.z, 8, 64);
        acc.w += __shfl_down(acc.w, 8, 64);
        if (grp == 0) ((float4*)sacc[wv])[c8] = acc;     // channels 4c8..4c8+3
        float o = bv;
        const float4* s4 = (const float4*)sacc[wv];
#pragma unroll
        for (int k4 = 0; k4 < 8; ++k4) {
            float4 a4 = s4[k4];
            o = fmaf(a4.x, W[(4 * k4 + 0) * 64 + lane], o);
            o = fmaf(a4.y, W[(4 * k4 + 1) * 64 + lane], o);
            o = fmaf(a4.z, W[(4 * k4 + 2) * 64 + lane], o);
            o = fmaf(a4.w, W[(4 * k4 + 3) * 64 + lane], o);
        }
        o = o / (1.0f + __expf(-o));
        o *= dis[node];
        out[(size_t)node * 64 + lane] = __float2half(o);
    }
}

// pool phase 1: 128-row chunks, segment-flush atomics into acc[G*64]
__global__ void k_pool_partial(const float* __restrict__ h, const int* __restrict__ batch,
                               float* __restrict__ acc, int n) {
    int c = threadIdx.x & 63, r = threadIdx.x >> 6;
    int base = blockIdx.x * 128;
    int end = base + 128; if (end > n) end = n;
    float part = 0.0f;
    int cur = -1;
    for (int i = base + r; i < end; i += 4) {
        int g = batch[i];
        if (g != cur) {
            if (cur >= 0) atomicAdd(&acc[cur * 64 + c], part);
            part = 0.0f;
            cur = g;
        }
        part += h[(size_t)i * 64 + c];
    }
    if (cur >= 0) atomicAdd(&acc[cur * 64 + c], part);
}

// pool phase 2: divide by per-graph count
__global__ void k_pool_final(const float* __restrict__ acc, const int* __restrict__ batch,
                             float* __restrict__ out, int n) {
    int idx = blockIdx.x * blockDim.x + threadIdx.x;   // G*64 threads
    int g = idx >> 6;
    int lo = lower_bound_i(batch, n, g);
    int hi = lower_bound_i(batch, n, g + 1);
    int cnt = hi - lo;
    out[idx] = acc[idx] / (float)(cnt > 0 ? cnt : 1);
}

extern "C" void kernel_launch(void* const* d_in, const int* in_sizes, int n_in,
                              void* d_out, int out_size, void* d_ws, size_t ws_size,
                              hipStream_t stream) {
    const float* x   = (const float*)d_in[0];
    const float* ew  = (const float*)d_in[1];
    const float* W1  = (const float*)d_in[2];
    const float* b1  = (const float*)d_in[3];
    const float* W2  = (const float*)d_in[4];
    const float* b2  = (const float*)d_in[5];
    const float* W3  = (const float*)d_in[6];
    const float* b3  = (const float*)d_in[7];
    const int*   eidx  = (const int*)d_in[8];
    const int*   batch = (const int*)d_in[9];
    float* out = (float*)d_out;

    const int E = in_sizes[1];       // 1,600,000
    const int N = in_sizes[9];       // 100,000 (< 131072: fits 17-bit src pack)
    const int G = 64;
    const int* src = eidx;
    const int* dst = eidx + E;

    // workspace: A/B (fp16 features) double as CSR-build scratch
    // (bedge in A: E*8B == N*64*2B exactly; hcnt/btot in B), both dead by the
    // time features first touch them. C holds the final fp32 layer for pooling.
    char* p = (char*)d_ws;
    __half* A     = (__half*)p;                p += (size_t)N * 64 * sizeof(__half);
    __half* B     = (__half*)p;                p += (size_t)N * 64 * sizeof(__half);
    float* C      = (float*)p;                 p += (size_t)N * 64 * sizeof(float);
    float* dis    = (float*)p;                 p += (size_t)N * sizeof(float);
    int*   rowptr = (int*)p;                   p += (size_t)(N + 1) * sizeof(int);
    int*   bbase  = (int*)p;                   p += (size_t)(NB + 1) * sizeof(int);
    float* acc    = (float*)p;                 p += (size_t)G * 64 * sizeof(float);
    p = (char*)(((uintptr_t)p + 7) & ~(uintptr_t)7);
    int2*  em     = (int2*)p;                  // E entries, 8B

    int2* bedge = (int2*)A;                    // E*8B == N*64*2B
    int*  hcnt  = (int*)B;                     // NB*PBLK*4B = 1MB
    int*  btot  = (int*)B + NB * PBLK;         // NB ints

    const int BT = 256;
    const int FUSED_BLOCKS = 3125;             // 12500 waves x 8 nodes = 100k

    // --- CSR build: LDS counting sort, zero global atomics ---
    k_bhist<<<PBLK, 256, 0, stream>>>(dst, hcnt, E);
    k_bscan<<<NB, 256, 0, stream>>>(hcnt, btot);
    k_bbase<<<1, 256, 0, stream>>>(btot, bbase, rowptr, N, E);
    k_bpart<<<PBLK, 256, 0, stream>>>(src, dst, ew, hcnt, bbase, bedge, E);
    k_bucket<<<NB, 256, 0, stream>>>(bedge, bbase, dis, rowptr, em, N);

    // --- layer 1: hs1 = fp16(dis*x) -> B ; fused agg+mm+silu*dis -> A ---
    // (B's hcnt scratch is dead after k_bpart; A's bedge dead after k_bucket)
    k_scale<<<(N * 32 + BT - 1) / BT, BT, 0, stream>>>(x, dis, (__half*)B, N * 32);
    k_aggmm32<<<FUSED_BLOCKS, BT, 0, stream>>>((__half*)B, em, rowptr, dis, W1, b1, A, N);

    // --- layer 2: fused agg+mm+silu*dis -> B ---
    k_aggmm64<true, __half><<<FUSED_BLOCKS, BT, 0, stream>>>(A, em, rowptr, dis, W2, b2, B, N);

    // --- layer 3: fused agg+mm+silu (raw fp32, for pooling) -> C ---
    k_aggmm64<false, float><<<FUSED_BLOCKS, BT, 0, stream>>>(B, em, rowptr, dis, W3, b3, C, N);

    // --- mean pool ---
    hipMemsetAsync(acc, 0, (size_t)G * 64 * sizeof(float), stream);
    k_pool_partial<<<(N + 127) / 128, BT, 0, stream>>>(C, batch, acc, N);
    k_pool_final<<<(G * 64) / BT, BT, 0, stream>>>(acc, batch, out, N);
}